// Round 10
// baseline (596.562 us; speedup 1.0000x reference)
//
#include <hip/hip_runtime.h>
#include <stdint.h>

#define B_ 64
#define S_ 512
#define K_ 1024
#define H_ 4096
#define C_ 32

typedef float  f32x4  __attribute__((ext_vector_type(4)));
typedef short  bf16x8 __attribute__((ext_vector_type(8)));
typedef unsigned short u16x8 __attribute__((ext_vector_type(8)));
typedef __attribute__((address_space(3))) unsigned int as3u32;
typedef const __attribute__((address_space(1))) unsigned int as1u32;

__device__ __forceinline__ unsigned short f2bf(float f) {
    unsigned u = __builtin_bit_cast(unsigned, f);
    u += 0x7fffu + ((u >> 16) & 1u);   // RNE
    return (unsigned short)(u >> 16);
}

// ---------------------------------------------------------------------------
// cat_ids may arrive as int32 or int64; detect on-device, normalize to i32.
__global__ void fix_cat_kernel(const void* __restrict__ cat_raw, int* __restrict__ cat32) {
    int t = threadIdx.x;                       // 64 threads = 1 wave
    const long long* c64 = (const long long*)cat_raw;
    const int*       c32 = (const int*)cat_raw;
    long long v = (t < 32) ? c64[t] : 0;
    int bad = (t < 32) && (v < 0 || v >= C_);
    unsigned long long m = __ballot(bad);
    if (m == 0ULL) {
        cat32[t] = (int)c64[t];
    } else {
        cat32[t] = c32[t];
    }
}

// ---------------------------------------------------------------------------
// x f32 -> bf16, vectorized 8 elems/thread
__global__ __launch_bounds__(256) void cvt_x_kernel(const float4* __restrict__ x,
                                                    uint4* __restrict__ xb, int n8) {
    int stride = gridDim.x * blockDim.x;
    for (int i = blockIdx.x * blockDim.x + threadIdx.x; i < n8; i += stride) {
        float4 a = x[2 * i], b = x[2 * i + 1];
        uint4 o;
        o.x = (unsigned)f2bf(a.x) | ((unsigned)f2bf(a.y) << 16);
        o.y = (unsigned)f2bf(a.z) | ((unsigned)f2bf(a.w) << 16);
        o.z = (unsigned)f2bf(b.x) | ((unsigned)f2bf(b.y) << 16);
        o.w = (unsigned)f2bf(b.z) | ((unsigned)f2bf(b.w) << 16);
        xb[i] = o;
    }
}

// ---------------------------------------------------------------------------
// W [C][K][H] f32 -> WT [C][H][K] bf16, LDS-tiled 64x64 transpose
__global__ __launch_bounds__(256) void cvt_w_kernel(const float* __restrict__ W,
                                                    unsigned short* __restrict__ WT) {
    __shared__ unsigned short tile[64 * 68];   // [k][n], padded stride 68
    const int nt = blockIdx.x;                 // 64 n-tiles
    const int kt = blockIdx.y;                 // 16 k-tiles
    const int c  = blockIdx.z;                 // 32 categories
    const int t  = threadIdx.x;

    const float* Wp = W + ((size_t)c << 22);
#pragma unroll
    for (int p = 0; p < 4; ++p) {
        int task = p * 256 + t;
        int kr = task >> 4;
        int nc = (task & 15) << 2;
        float4 v = *(const float4*)(Wp + (size_t)(kt * 64 + kr) * H_ + nt * 64 + nc);
        tile[kr * 68 + nc + 0] = f2bf(v.x);
        tile[kr * 68 + nc + 1] = f2bf(v.y);
        tile[kr * 68 + nc + 2] = f2bf(v.z);
        tile[kr * 68 + nc + 3] = f2bf(v.w);
    }
    __syncthreads();

    unsigned short* WTp = WT + ((size_t)c << 22);
#pragma unroll
    for (int q = 0; q < 2; ++q) {
        int task = q * 256 + t;
        int nl = task >> 3;
        int ko = (task & 7) << 3;
        u16x8 o;
#pragma unroll
        for (int j = 0; j < 8; ++j) o[j] = tile[(ko + j) * 68 + nl];
        *(u16x8*)(WTp + (size_t)(nt * 64 + nl) * K_ + kt * 64 + ko) = o;
    }
}

// ---------------------------------------------------------------------------
// Batched GEMM, occupancy-first version.
//   128x256 tile, BK=32 (32 K-tiles), 8 waves (2Mx4N), per-wave 64x64
//   -> acc = 16 x f32x4 = 64 regs/lane. __launch_bounds__(512, 4): 128-reg
//   budget, steady-state live ~116-126 regs -> NO spill, 2 blocks/CU
//   resident (LDS 2x72=144 <= 160 KiB) = 4 waves/SIMD. The second,
//   barrier-independent block is what finally overlaps LDS-read bursts
//   with MFMA clusters (rounds 2-9: 1 block/CU, perfect alternation,
//   370 us invariant across 7 schedule variants).
//   3-slot LDS ring (24 KiB each: A 8K | B 16K), stage distance 2,
//   ONE barrier + ONE counted vmcnt(3) per K-tile (never 0 in-loop).
//   No setprio / no lgkm asm / no sched_barrier (m190/m141: null or harmful).
// Race margins:
//   - slot T ready before reads(T): vmcnt(3)+barrier at iteration T-1.
//   - GLD(T+2) overwrites slot((T-1))%3: last reads of that slot issued
//     pre-barrier(T-1); GLD issues post-barrier(T-1)+MFMA cluster (~600cyc)
//     >> ds_read latency (~120cyc).
__global__ __launch_bounds__(512, 4) void gemm7_kernel(
    const unsigned short* __restrict__ xb,   // [B][S][K] bf16
    const unsigned short* __restrict__ WT,   // [C][H][K] bf16
    const float* __restrict__ bias,          // [C][H]
    const int* __restrict__ cat,             // [B]
    float* __restrict__ out)                 // [B][S][H]
{
    extern __shared__ __align__(16) char smem[];   // 3 x (A 8K | B 16K) = 72K

    const int t    = threadIdx.x;
    const int lane = t & 63;
    const int w    = t >> 6;            // 0..7
    const int wm   = w >> 2;            // 0..1
    const int wn   = w & 3;             // 0..3
    const int lo   = lane & 15;
    const int hi   = lane >> 4;         // 0..3

    // XCD-aware bijective swizzle (4096 % 8 == 0)
    const int wg = (blockIdx.x & 7) * 512 + (blockIdx.x >> 3);
    const int bn = wg & 15;             // 16 n-tiles of 256
    const int bm = (wg >> 4) & 3;       // 4 m-tiles of 128
    const int bb = wg >> 6;             // 64 batches

    const int c = cat[bb];

    const unsigned short* Ap = xb + (size_t)bb * (S_ * K_) + (size_t)(bm * 128) * K_;
    const unsigned short* Bp = WT + (size_t)c * ((size_t)H_ * K_) + (size_t)(bn * 256) * K_;

    // staging: each gload_lds covers 16 rows x 64 B. A (128 rows) = chunk w;
    // B (256 rows) = chunks w and 8+w. LDS dest linear; global source
    // pre-swizzled (verified rounds 6-9: 0 conflicts):
    // logical 16B-slot = (lane&3) ^ ((row>>1)&3) = (lane&3) ^ ((lane>>3)&3).
    const int srow  = lane >> 2;
    const int sslot = (lane & 3) ^ ((lane >> 3) & 3);
    const char* sA0 = (const char*)(Ap + (size_t)(w * 16 + srow) * K_) + sslot * 16;
    const char* sB0 = (const char*)(Bp + (size_t)(w * 16 + srow) * K_) + sslot * 16;
    const char* sB1 = (const char*)(Bp + (size_t)((128 + w * 16) + srow) * K_) + sslot * 16;
    const int dcA  = w * 1024;                  // A region: slot + 0
    const int dcB0 = 8192 + w * 1024;           // B region: slot + 8K
    const int dcB1 = 8192 + (8 + w) * 1024;

    // fragment read offsets: row stride 64 B, phys slot = hi ^ ((row>>1)&3);
    // frag bases are multiples of 16 rows so (row>>1)&3 == (lo>>1)&3.
    const int xslot = (hi ^ ((lo >> 1) & 3)) << 4;
    int aoff[4], boff[4];
#pragma unroll
    for (int mi = 0; mi < 4; ++mi) aoff[mi] = (wm * 64 + mi * 16 + lo) * 64 + xslot;
#pragma unroll
    for (int ni = 0; ni < 4; ++ni) boff[ni] = 8192 + (wn * 64 + ni * 16 + lo) * 64 + xslot;

    f32x4 acc[4][4];
#pragma unroll
    for (int mi = 0; mi < 4; ++mi)
#pragma unroll
        for (int ni = 0; ni < 4; ++ni) acc[mi][ni] = f32x4{0.f, 0.f, 0.f, 0.f};

#define GLD(src_, dst_) __builtin_amdgcn_global_load_lds((as1u32*)(src_), (as3u32*)(dst_), 16, 0, 0)

    // prologue: stage tiles 0,1 into slots 0,1 (6 gloads); tile 0 landed via
    // counted vmcnt(3) (tile 1's 3 stay in flight).
    {
        char* s0 = smem;
        char* s1 = smem + 24576;
        GLD(sA0 + 0,  s0 + dcA); GLD(sB0 + 0,  s0 + dcB0); GLD(sB1 + 0,  s0 + dcB1);
        GLD(sA0 + 64, s1 + dcA); GLD(sB0 + 64, s1 + dcB0); GLD(sB1 + 64, s1 + dcB1);
    }
    asm volatile("s_waitcnt vmcnt(3)" ::: "memory");
    __builtin_amdgcn_s_barrier();

    int rs = 0;   // read slot  = T % 3
    int ws = 2;   // write slot = (T+2) % 3

#pragma unroll 1
    for (int T = 0; T < 32; ++T) {
        const char* rb = smem + rs * 24576;
        char*       wb = smem + ws * 24576;
        const int soff = ((T + 2) & 31) * 64;   // tail wraps into dead slots
        bf16x8 av[4], bv[4];

        // reads (12 x ds_read_b128) + stage tile T+2 (3 gloads), then one
        // counted vmcnt (tile T+1 landed for next iteration) + one barrier.
#pragma unroll
        for (int mi = 0; mi < 4; ++mi) av[mi] = *(const bf16x8*)(rb + aoff[mi]);
#pragma unroll
        for (int ni = 0; ni < 4; ++ni) bv[ni] = *(const bf16x8*)(rb + boff[ni]);
        GLD(sA0 + soff, wb + dcA);
        GLD(sB0 + soff, wb + dcB0);
        GLD(sB1 + soff, wb + dcB1);
        asm volatile("s_waitcnt vmcnt(3)" ::: "memory");
        __builtin_amdgcn_s_barrier();

        // 16 MFMA (compiler inserts minimal lgkmcnt before first frag use)
#pragma unroll
        for (int mi = 0; mi < 4; ++mi)
#pragma unroll
            for (int ni = 0; ni < 4; ++ni)
                acc[mi][ni] = __builtin_amdgcn_mfma_f32_16x16x32_bf16(
                    bv[ni], av[mi], acc[mi][ni], 0, 0, 0);

        rs = (rs == 2) ? 0 : rs + 1;
        ws = (ws == 2) ? 0 : ws + 1;
    }
#undef GLD

    // drain wrap-staged loads before block exit
    asm volatile("s_waitcnt vmcnt(0)" ::: "memory");

    // epilogue (verified layout). Operand-swapped D: n = frag + hi*4 + reg,
    // m = lo; 4 hi values cover 64 B contiguous per row.
    float* outp = out + ((size_t)bb * S_ + bm * 128 + wm * 64) * H_ + bn * 256 + wn * 64;
    const float* bp = bias + (size_t)c * H_ + bn * 256 + wn * 64;
#pragma unroll
    for (int ni = 0; ni < 4; ++ni) {
        const int nf = ni * 16 + hi * 4;
        const f32x4 b4 = *(const f32x4*)(bp + nf);
#pragma unroll
        for (int mi = 0; mi < 4; ++mi) {
            const int mf = mi * 16 + lo;
            f32x4 v = acc[mi][ni];
            v.x += b4.x; v.y += b4.y; v.z += b4.z; v.w += b4.w;
            __builtin_nontemporal_store(v, (f32x4*)(outp + (size_t)mf * H_ + nf));
        }
    }
}

// ---------------------------------------------------------------------------
// Fallback (ws too small): correct but slow f32 vector-ALU kernel.
__global__ __launch_bounds__(256) void fallback_kernel(
    const float* __restrict__ x, const int* __restrict__ cat,
    const float* __restrict__ W, const float* __restrict__ bias,
    float* __restrict__ out)
{
    __shared__ float xs[K_];
    int bs = blockIdx.x;
    int bb = bs >> 9;
    int c  = cat[bb];
    const float* xp = x + (size_t)bs * K_;
    for (int i = threadIdx.x; i < K_ / 4; i += 256)
        ((float4*)xs)[i] = ((const float4*)xp)[i];
    __syncthreads();

    int h = blockIdx.y * 1024 + threadIdx.x * 4;
    const float* Wp = W + (size_t)c * K_ * H_ + h;
    float a0 = 0.f, a1 = 0.f, a2 = 0.f, a3 = 0.f;
    for (int k = 0; k < K_; ++k) {
        float xv = xs[k];
        float4 wv = *(const float4*)(Wp + (size_t)k * H_);
        a0 += xv * wv.x; a1 += xv * wv.y; a2 += xv * wv.z; a3 += xv * wv.w;
    }
    float4 bv = *(const float4*)(bias + c * H_ + h);
    float4 o; o.x = a0 + bv.x; o.y = a1 + bv.y; o.z = a2 + bv.z; o.w = a3 + bv.w;
    *(float4*)(out + (size_t)bs * H_ + h) = o;
}

// ---------------------------------------------------------------------------
extern "C" void kernel_launch(void* const* d_in, const int* in_sizes, int n_in,
                              void* d_out, int out_size, void* d_ws, size_t ws_size,
                              hipStream_t stream) {
    const float* x        = (const float*)d_in[0];
    const void*  cat_raw  = d_in[1];
    const float* W        = (const float*)d_in[2];
    const float* bias     = (const float*)d_in[3];
    float*       out      = (float*)d_out;

    const size_t CAT_BYTES = 256;
    const size_t XB_OFF    = 256;
    const size_t XB_BYTES  = (size_t)B_ * S_ * K_ * 2;          // 64 MiB
    const size_t WT_OFF    = XB_OFF + XB_BYTES;
    const size_t WT_BYTES  = (size_t)C_ * H_ * K_ * 2;          // 256 MiB
    const size_t NEED      = WT_OFF + WT_BYTES;

    const int* catp;
    if (ws_size >= CAT_BYTES) {
        int* cat32 = (int*)d_ws;
        fix_cat_kernel<<<1, 64, 0, stream>>>(cat_raw, cat32);
        catp = cat32;
    } else {
        catp = (const int*)cat_raw;
    }

    if (ws_size >= NEED) {
        unsigned short* xb = (unsigned short*)((char*)d_ws + XB_OFF);
        unsigned short* WT = (unsigned short*)((char*)d_ws + WT_OFF);
        cvt_x_kernel<<<2048, 256, 0, stream>>>((const float4*)x, (uint4*)xb,
                                               (int)((size_t)B_ * S_ * K_ / 8));
        dim3 gw(64, 16, 32);
        cvt_w_kernel<<<gw, 256, 0, stream>>>(W, WT);
        (void)hipFuncSetAttribute((const void*)gemm7_kernel,
                                  hipFuncAttributeMaxDynamicSharedMemorySize, 73728);
        gemm7_kernel<<<4096, 512, 73728, stream>>>(xb, WT, bias, catp, out);
    } else {
        dim3 g(B_ * S_, H_ / 1024);
        fallback_kernel<<<g, 256, 0, stream>>>(x, catp, W, bias, out);
    }
}

// Round 11
// 535.655 us; speedup vs baseline: 1.1137x; 1.1137x over previous
//
#include <hip/hip_runtime.h>
#include <stdint.h>

#define B_ 64
#define S_ 512
#define K_ 1024
#define H_ 4096
#define C_ 32

typedef float  f32x4  __attribute__((ext_vector_type(4)));
typedef short  bf16x8 __attribute__((ext_vector_type(8)));
typedef unsigned short u16x8 __attribute__((ext_vector_type(8)));
typedef __attribute__((address_space(3))) unsigned int as3u32;
typedef const __attribute__((address_space(1))) unsigned int as1u32;

__device__ __forceinline__ unsigned short f2bf(float f) {
    unsigned u = __builtin_bit_cast(unsigned, f);
    u += 0x7fffu + ((u >> 16) & 1u);   // RNE
    return (unsigned short)(u >> 16);
}

// ---------------------------------------------------------------------------
// cat_ids may arrive as int32 or int64; detect on-device, normalize to i32.
__global__ void fix_cat_kernel(const void* __restrict__ cat_raw, int* __restrict__ cat32) {
    int t = threadIdx.x;                       // 64 threads = 1 wave
    const long long* c64 = (const long long*)cat_raw;
    const int*       c32 = (const int*)cat_raw;
    long long v = (t < 32) ? c64[t] : 0;
    int bad = (t < 32) && (v < 0 || v >= C_);
    unsigned long long m = __ballot(bad);
    if (m == 0ULL) {
        cat32[t] = (int)c64[t];
    } else {
        cat32[t] = c32[t];
    }
}

// ---------------------------------------------------------------------------
// x f32 -> bf16, vectorized 8 elems/thread
__global__ __launch_bounds__(256) void cvt_x_kernel(const float4* __restrict__ x,
                                                    uint4* __restrict__ xb, int n8) {
    int stride = gridDim.x * blockDim.x;
    for (int i = blockIdx.x * blockDim.x + threadIdx.x; i < n8; i += stride) {
        float4 a = x[2 * i], b = x[2 * i + 1];
        uint4 o;
        o.x = (unsigned)f2bf(a.x) | ((unsigned)f2bf(a.y) << 16);
        o.y = (unsigned)f2bf(a.z) | ((unsigned)f2bf(a.w) << 16);
        o.z = (unsigned)f2bf(b.x) | ((unsigned)f2bf(b.y) << 16);
        o.w = (unsigned)f2bf(b.z) | ((unsigned)f2bf(b.w) << 16);
        xb[i] = o;
    }
}

// ---------------------------------------------------------------------------
// W [C][K][H] f32 -> WT [C][H][K] bf16, LDS-tiled 64x64 transpose
__global__ __launch_bounds__(256) void cvt_w_kernel(const float* __restrict__ W,
                                                    unsigned short* __restrict__ WT) {
    __shared__ unsigned short tile[64 * 68];   // [k][n], padded stride 68
    const int nt = blockIdx.x;                 // 64 n-tiles
    const int kt = blockIdx.y;                 // 16 k-tiles
    const int c  = blockIdx.z;                 // 32 categories
    const int t  = threadIdx.x;

    const float* Wp = W + ((size_t)c << 22);
#pragma unroll
    for (int p = 0; p < 4; ++p) {
        int task = p * 256 + t;
        int kr = task >> 4;
        int nc = (task & 15) << 2;
        float4 v = *(const float4*)(Wp + (size_t)(kt * 64 + kr) * H_ + nt * 64 + nc);
        tile[kr * 68 + nc + 0] = f2bf(v.x);
        tile[kr * 68 + nc + 1] = f2bf(v.y);
        tile[kr * 68 + nc + 2] = f2bf(v.z);
        tile[kr * 68 + nc + 3] = f2bf(v.w);
    }
    __syncthreads();

    unsigned short* WTp = WT + ((size_t)c << 22);
#pragma unroll
    for (int q = 0; q < 2; ++q) {
        int task = q * 256 + t;
        int nl = task >> 3;
        int ko = (task & 7) << 3;
        u16x8 o;
#pragma unroll
        for (int j = 0; j < 8; ++j) o[j] = tile[(ko + j) * 68 + nl];
        *(u16x8*)(WTp + (size_t)(nt * 64 + nl) * K_ + kt * 64 + ko) = o;
    }
}

// ---------------------------------------------------------------------------
// PERSISTENT round-major batched GEMM.
//   Core = round-9 fence-free body (verified: 370 us, 0 conflicts, passed):
//   256x256 tile, BK=32, 8 waves (2Mx4N), per-wave 128x64 (acc 128 regs),
//   3-slot LDS ring (96 KiB), stage distance 2, ONE counted vmcnt(4)/tile.
//   NEW: 256 blocks (1/CU) x 8 ROUND-MAJOR assignments: block p does
//   a = r*256 + p. Since a === p (mod 8), the XCD decode gives the SAME
//   instantaneous working set as the non-persistent grid (round-5 lesson:
//   block-major order thrashed L2, FETCH 806 MB). The ring rolls across
//   assignment boundaries: pipeline fills once per kernel (not 8x), the
//   epilogue stores overlap the next assignment's staged tiles, vmcnt never
//   drains to 0 until kernel end.
__global__ __launch_bounds__(512, 2) void gemm8_kernel(
    const unsigned short* __restrict__ xb,   // [B][S][K] bf16
    const unsigned short* __restrict__ WT,   // [C][H][K] bf16
    const float* __restrict__ bias,          // [C][H]
    const int* __restrict__ cat,             // [B]
    float* __restrict__ out)                 // [B][S][H]
{
    extern __shared__ __align__(16) char smem[];   // 3 slots x (A 16K | B 16K)

    const int t    = threadIdx.x;
    const int lane = t & 63;
    const int w    = t >> 6;            // 0..7
    const int wm   = w >> 2;            // 0..1
    const int wn   = w & 3;             // 0..3
    const int lo   = lane & 15;
    const int hi   = lane >> 4;         // 0..3

    const int p = blockIdx.x;           // 0..255, p&7 = XCD (round-robin)

    // staging lane geometry (verified rounds 6-9: 0 conflicts).
    const int srow  = lane >> 2;
    const int sslot = (lane & 3) ^ ((lane >> 3) & 3);
    const size_t re0 = (size_t)((0 * 8 + w) * 16 + srow) * K_;   // chunk w
    const size_t re1 = (size_t)((1 * 8 + w) * 16 + srow) * K_;   // chunk 8+w
    const int sb  = sslot * 16;
    const int dc0 = (0 * 8 + w) * 1024;
    const int dc1 = (1 * 8 + w) * 1024;

    // fragment read offsets: row stride 64 B, phys slot = hi ^ ((row>>1)&3).
    const int xslot = (hi ^ ((lo >> 1) & 3)) << 4;
    int aoff[8], boff[4];
#pragma unroll
    for (int mi = 0; mi < 8; ++mi) aoff[mi] = (wm * 128 + mi * 16 + lo) * 64 + xslot;
#pragma unroll
    for (int ni = 0; ni < 4; ++ni) boff[ni] = 16384 + (wn * 64 + ni * 16 + lo) * 64 + xslot;

    f32x4 acc[8][4];
#pragma unroll
    for (int mi = 0; mi < 8; ++mi)
#pragma unroll
        for (int ni = 0; ni < 4; ++ni) acc[mi][ni] = f32x4{0.f, 0.f, 0.f, 0.f};

    // round-major assignment decode: aa = r*256 + p; wg = (aa&7)*256 + aa>>3.
#define DECODE(r_, A0_, A1_, B0_, B1_, bn_, bm_, bb_, c_) do {                     \
    int aa__ = (r_) * 256 + p;                                                     \
    int wg__ = (aa__ & 7) * 256 + (aa__ >> 3);                                     \
    bn_ = wg__ & 15; bm_ = (wg__ >> 4) & 1; bb_ = wg__ >> 5;                       \
    c_ = cat[bb_];                                                                 \
    const unsigned short* Ap__ = xb + (size_t)bb_ * (S_ * K_) + (size_t)(bm_ * 256) * K_; \
    const unsigned short* Bp__ = WT + (size_t)c_ * ((size_t)H_ * K_) + (size_t)(bn_ * 256) * K_; \
    A0_ = (const char*)(Ap__ + re0) + sb; A1_ = (const char*)(Ap__ + re1) + sb;    \
    B0_ = (const char*)(Bp__ + re0) + sb; B1_ = (const char*)(Bp__ + re1) + sb;    \
} while (0)

#define GLD(src_, dst_) __builtin_amdgcn_global_load_lds((as1u32*)(src_), (as3u32*)(dst_), 16, 0, 0)

    const char *cA0, *cA1, *cB0, *cB1;   // current assignment staging bases
    const char *nA0, *nA1, *nB0, *nB1;   // next assignment staging bases
    int bn, bm, bb, cc, nbn, nbm, nbb, ncc;

    DECODE(0, cA0, cA1, cB0, cB1, bn, bm, bb, cc);

    // prologue (once per kernel): stage tiles 0,1 into slots 0,1.
    {
        char* s0 = smem;
        char* s1 = smem + 32768;
        GLD(cA0 + 0,  s0 + dc0);          GLD(cB0 + 0,  s0 + 16384 + dc0);
        GLD(cA1 + 0,  s0 + dc1);          GLD(cB1 + 0,  s0 + 16384 + dc1);
        GLD(cA0 + 64, s1 + dc0);          GLD(cB0 + 64, s1 + 16384 + dc0);
        GLD(cA1 + 64, s1 + dc1);          GLD(cB1 + 64, s1 + 16384 + dc1);
    }
    asm volatile("s_waitcnt vmcnt(4)" ::: "memory");
    __builtin_amdgcn_s_barrier();

    int rs = 0;   // read slot  = g % 3  (g = global tile counter, runs on)
    int ws = 2;   // write slot = (g+2) % 3

    for (int r = 0; r < 8; ++r) {
        const int rn = (r < 7) ? (r + 1) : 7;   // last round wraps into itself
        DECODE(rn, nA0, nA1, nB0, nB1, nbn, nbm, nbb, ncc);

#pragma unroll 1
        for (int T = 0; T < 32; ++T) {
            const char* rb = smem + rs * 32768;
            char*       wb = smem + ws * 32768;
            const bool  nx = (T >= 30);
            const char* pA0 = nx ? nA0 : cA0;
            const char* pA1 = nx ? nA1 : cA1;
            const char* pB0 = nx ? nB0 : cB0;
            const char* pB1 = nx ? nB1 : cB1;
            const int soff = ((T + 2) & 31) * 64;
            bf16x8 av[4], bv[4], aw[4];

            // ---- ph1: read A-frags 0-3 + all B; stage A0,B0 of tile g+2
#pragma unroll
            for (int mi = 0; mi < 4; ++mi) av[mi] = *(const bf16x8*)(rb + aoff[mi]);
#pragma unroll
            for (int ni = 0; ni < 4; ++ni) bv[ni] = *(const bf16x8*)(rb + boff[ni]);
            GLD(pA0 + soff, wb + dc0);
            GLD(pB0 + soff, wb + 16384 + dc0);
            __builtin_amdgcn_s_barrier();
            __builtin_amdgcn_s_setprio(1);
#pragma unroll
            for (int mi = 0; mi < 4; ++mi)
#pragma unroll
                for (int ni = 0; ni < 4; ++ni)
                    acc[mi][ni] = __builtin_amdgcn_mfma_f32_16x16x32_bf16(
                        bv[ni], av[mi], acc[mi][ni], 0, 0, 0);
            __builtin_amdgcn_s_setprio(0);

            // ---- ph2: read A-frags 4-7; stage A1,B1; counted vmcnt
#pragma unroll
            for (int mi = 0; mi < 4; ++mi) aw[mi] = *(const bf16x8*)(rb + aoff[mi + 4]);
            GLD(pA1 + soff, wb + dc1);
            GLD(pB1 + soff, wb + 16384 + dc1);
            asm volatile("s_waitcnt vmcnt(4)" ::: "memory");   // tile g+1 landed
            __builtin_amdgcn_s_barrier();
            __builtin_amdgcn_s_setprio(1);
#pragma unroll
            for (int mi = 0; mi < 4; ++mi)
#pragma unroll
                for (int ni = 0; ni < 4; ++ni)
                    acc[mi + 4][ni] = __builtin_amdgcn_mfma_f32_16x16x32_bf16(
                        bv[ni], aw[mi], acc[mi + 4][ni], 0, 0, 0);
            __builtin_amdgcn_s_setprio(0);

            rs = (rs == 2) ? 0 : rs + 1;
            ws = (ws == 2) ? 0 : ws + 1;
        }

        // ---- epilogue for assignment r (no barrier: overlaps next tiles)
        {
            float* outp = out + ((size_t)bb * S_ + bm * 256 + wm * 128) * H_
                        + bn * 256 + wn * 64;
            const float* bp = bias + (size_t)cc * H_ + bn * 256 + wn * 64;
#pragma unroll
            for (int ni = 0; ni < 4; ++ni) {
                const int nf = ni * 16 + hi * 4;
                const f32x4 b4 = *(const f32x4*)(bp + nf);
#pragma unroll
                for (int mi = 0; mi < 8; ++mi) {
                    const int mf = mi * 16 + lo;
                    f32x4 v = acc[mi][ni];
                    v.x += b4.x; v.y += b4.y; v.z += b4.z; v.w += b4.w;
                    __builtin_nontemporal_store(v, (f32x4*)(outp + (size_t)mf * H_ + nf));
                    acc[mi][ni] = f32x4{0.f, 0.f, 0.f, 0.f};
                }
            }
        }

        cA0 = nA0; cA1 = nA1; cB0 = nB0; cB1 = nB1;
        bn = nbn; bm = nbm; bb = nbb; cc = ncc;
    }
#undef GLD
#undef DECODE

    // drain wrap-staged loads before block exit
    asm volatile("s_waitcnt vmcnt(0)" ::: "memory");
}

// ---------------------------------------------------------------------------
// Fallback (ws too small): correct but slow f32 vector-ALU kernel.
__global__ __launch_bounds__(256) void fallback_kernel(
    const float* __restrict__ x, const int* __restrict__ cat,
    const float* __restrict__ W, const float* __restrict__ bias,
    float* __restrict__ out)
{
    __shared__ float xs[K_];
    int bs = blockIdx.x;
    int bb = bs >> 9;
    int c  = cat[bb];
    const float* xp = x + (size_t)bs * K_;
    for (int i = threadIdx.x; i < K_ / 4; i += 256)
        ((float4*)xs)[i] = ((const float4*)xp)[i];
    __syncthreads();

    int h = blockIdx.y * 1024 + threadIdx.x * 4;
    const float* Wp = W + (size_t)c * K_ * H_ + h;
    float a0 = 0.f, a1 = 0.f, a2 = 0.f, a3 = 0.f;
    for (int k = 0; k < K_; ++k) {
        float xv = xs[k];
        float4 wv = *(const float4*)(Wp + (size_t)k * H_);
        a0 += xv * wv.x; a1 += xv * wv.y; a2 += xv * wv.z; a3 += xv * wv.w;
    }
    float4 bv = *(const float4*)(bias + c * H_ + h);
    float4 o; o.x = a0 + bv.x; o.y = a1 + bv.y; o.z = a2 + bv.z; o.w = a3 + bv.w;
    *(float4*)(out + (size_t)bs * H_ + h) = o;
}

// ---------------------------------------------------------------------------
extern "C" void kernel_launch(void* const* d_in, const int* in_sizes, int n_in,
                              void* d_out, int out_size, void* d_ws, size_t ws_size,
                              hipStream_t stream) {
    const float* x        = (const float*)d_in[0];
    const void*  cat_raw  = d_in[1];
    const float* W        = (const float*)d_in[2];
    const float* bias     = (const float*)d_in[3];
    float*       out      = (float*)d_out;

    const size_t CAT_BYTES = 256;
    const size_t XB_OFF    = 256;
    const size_t XB_BYTES  = (size_t)B_ * S_ * K_ * 2;          // 64 MiB
    const size_t WT_OFF    = XB_OFF + XB_BYTES;
    const size_t WT_BYTES  = (size_t)C_ * H_ * K_ * 2;          // 256 MiB
    const size_t NEED      = WT_OFF + WT_BYTES;

    const int* catp;
    if (ws_size >= CAT_BYTES) {
        int* cat32 = (int*)d_ws;
        fix_cat_kernel<<<1, 64, 0, stream>>>(cat_raw, cat32);
        catp = cat32;
    } else {
        catp = (const int*)cat_raw;
    }

    if (ws_size >= NEED) {
        unsigned short* xb = (unsigned short*)((char*)d_ws + XB_OFF);
        unsigned short* WT = (unsigned short*)((char*)d_ws + WT_OFF);
        cvt_x_kernel<<<2048, 256, 0, stream>>>((const float4*)x, (uint4*)xb,
                                               (int)((size_t)B_ * S_ * K_ / 8));
        dim3 gw(64, 16, 32);
        cvt_w_kernel<<<gw, 256, 0, stream>>>(W, WT);
        (void)hipFuncSetAttribute((const void*)gemm8_kernel,
                                  hipFuncAttributeMaxDynamicSharedMemorySize, 98304);
        gemm8_kernel<<<256, 512, 98304, stream>>>(xb, WT, bias, catp, out);
    } else {
        dim3 g(B_ * S_, H_ / 1024);
        fallback_kernel<<<g, 256, 0, stream>>>(x, catp, W, bias, out);
    }
}